// Round 1
// baseline (29.277 us; speedup 1.0000x reference)
//
#include <hip/hip_runtime.h>

// EWMA along seq dim: s_0 = x_0; s_t = alpha*x_t + (1-alpha)*s_{t-1}
// x: (16, 8192, 128) fp32, feature dim contiguous.
//
// Strategy: chunked scan with halo warm-start. (1-alpha)^64 ~ 1.2e-10 for
// alpha=0.3, so a 64-element halo with zero init reproduces the exact state
// to ~1e-10 -- vastly below the 6.9e-2 absmax threshold. Chunk 0 is exact.

constexpr int SEQ   = 8192;
constexpr int FEAT  = 128;
constexpr int BATCH = 16;
constexpr int CHUNK = 128;  // outputs per thread
constexpr int HALO  = 64;   // warm-up reads per thread (no writes)
constexpr int NCHUNK = SEQ / CHUNK;  // 64

__global__ __launch_bounds__(256) void TemporalSmoothing_kernel(
    const float* __restrict__ x,
    const float* __restrict__ alpha_p,
    float* __restrict__ out) {
    const float a = alpha_p[0];
    const float b = 1.0f - a;

    const int f     = threadIdx.x;                       // 0..127 feature
    const int chunk = blockIdx.x * blockDim.y + threadIdx.y;  // 0..63
    const int batch = blockIdx.y;                        // 0..15

    const size_t base = (size_t)batch * SEQ * FEAT + f;
    const float* xp = x + base;
    float*       op = out + base;

    const int t0 = chunk * CHUNK;
    float s;
    int tstart;

    if (chunk == 0) {
        // exact start: s_0 = x_0
        s = xp[0];
        op[0] = s;
        tstart = 1;
    } else {
        // halo warm-start: zero init, 64 decay steps -> error ~ (1-a)^64
        s = 0.0f;
        #pragma unroll 8
        for (int t = t0 - HALO; t < t0; ++t) {
            s = fmaf(b, s, a * xp[(size_t)t * FEAT]);
        }
        tstart = t0;
    }

    #pragma unroll 8
    for (int t = tstart; t < t0 + CHUNK; ++t) {
        s = fmaf(b, s, a * xp[(size_t)t * FEAT]);
        op[(size_t)t * FEAT] = s;
    }
}

extern "C" void kernel_launch(void* const* d_in, const int* in_sizes, int n_in,
                              void* d_out, int out_size, void* d_ws, size_t ws_size,
                              hipStream_t stream) {
    const float* x     = (const float*)d_in[0];
    const float* alpha = (const float*)d_in[1];
    float*       out   = (float*)d_out;

    dim3 block(FEAT, 2);                 // 256 threads: 128 features x 2 chunks
    dim3 grid(NCHUNK / 2, BATCH);        // 32 x 16 = 512 blocks
    TemporalSmoothing_kernel<<<grid, block, 0, stream>>>(x, alpha, out);
}